// Round 3
// baseline (642.318 us; speedup 1.0000x reference)
//
#include <hip/hip_runtime.h>
#include <math.h>

#define N_ROWS 131072
#define D 512
#define BLOCKS 2048
#define WPB 4
#define NWAVES (BLOCKS * WPB)                  // 8192 waves
#define STEPS (N_ROWS / NWAVES)                // 16 strided steps per wave
#define EPS 1e-6f

// s_waitcnt imm (gfx9): lgkmcnt=0xF (no wait), expcnt=0x7 (no wait), vmcnt=N (bits [3:0],[15:14])
#define WAIT_VM(N) __builtin_amdgcn_s_waitcnt(0x0F70 | ((N) & 0xF) | ((((N) >> 4) & 3) << 14))
#define PIN() __builtin_amdgcn_sched_barrier(0)

// numerically stable, branchless softplus: max(x,0) + log1p(exp(-|x|))
__device__ __forceinline__ float softplusf(float x) {
    return fmaxf(x, 0.0f) + log1pf(__expf(-fabsf(x)));
}

// one slot = one row of both inputs: 2 x float4 per input per lane (16 VGPRs)
struct Slot { float4 a0, a1, b0, b1; };

// row for step K: gwave + K*NWAVES  ->  float offset K * NWAVES*D from the wave base
#define ISSUE(S, K) do {                                          \
    const float* _p1 = pRow1 + (size_t)(K) * ((size_t)NWAVES * D);\
    const float* _p2 = pRow2 + (size_t)(K) * ((size_t)NWAVES * D);\
    S.a0 = *(const float4*)(_p1);                                 \
    S.a1 = *(const float4*)(_p1 + 256);                           \
    S.b0 = *(const float4*)(_p2);                                 \
    S.b1 = *(const float4*)(_p2 + 256);                           \
} while (0)

__device__ __forceinline__ void proc_tile(const Slot& s, int k, int lane,
                                          float& myDot, float& myS1, float& myS2) {
    float dot = s.a0.x * s.b0.x + s.a0.y * s.b0.y + s.a0.z * s.b0.z + s.a0.w * s.b0.w
              + s.a1.x * s.b1.x + s.a1.y * s.b1.y + s.a1.z * s.b1.z + s.a1.w * s.b1.w;
    float s1  = s.a0.x * s.a0.x + s.a0.y * s.a0.y + s.a0.z * s.a0.z + s.a0.w * s.a0.w
              + s.a1.x * s.a1.x + s.a1.y * s.a1.y + s.a1.z * s.a1.z + s.a1.w * s.a1.w;
    float s2  = s.b0.x * s.b0.x + s.b0.y * s.b0.y + s.b0.z * s.b0.z + s.b0.w * s.b0.w
              + s.b1.x * s.b1.x + s.b1.y * s.b1.y + s.b1.z * s.b1.z + s.b1.w * s.b1.w;
    #pragma unroll
    for (int off = 32; off > 0; off >>= 1) {
        dot += __shfl_xor(dot, off);
        s1  += __shfl_xor(s1, off);
        s2  += __shfl_xor(s2, off);
    }
    // lane k keeps this step's row result
    if (lane == k) { myDot = dot; myS1 = s1; myS2 = s2; }
}

__global__ __launch_bounds__(256, 8) void binloss_main(
    const float* __restrict__ o1, const float* __restrict__ o2,
    const int* __restrict__ target,
    float* __restrict__ sums, int* __restrict__ icnt,
    unsigned int* __restrict__ done, float* __restrict__ out) {

    __shared__ float sPos[WPB], sNeg[WPB];
    __shared__ int sCnt[WPB];

    const int lane = threadIdx.x & 63;
    const int wave = threadIdx.x >> 6;
    const int gwave = blockIdx.x * WPB + wave;

    // wave base: row gwave, this lane's 2-float4 chunk
    const float* pRow1 = o1 + (size_t)gwave * D + lane * 4;
    const float* pRow2 = o2 + (size_t)gwave * D + lane * 4;

    float myDot = 0.0f, myS1 = 1.0f, myS2 = 1.0f;

    Slot sA, sB;

    // depth-2 pipeline, counted vmcnt(4): next slot's 4 loads stay in flight
    ISSUE(sA, 0);
    #pragma unroll
    for (int k = 0; k < STEPS; k += 2) {
        if (k + 1 < STEPS) { ISSUE(sB, k + 1); PIN(); WAIT_VM(4); PIN(); }
        else               { PIN(); WAIT_VM(0); PIN(); }
        proc_tile(sA, k, lane, myDot, myS1, myS2);

        if (k + 2 < STEPS) { ISSUE(sA, k + 2); PIN(); WAIT_VM(4); PIN(); }
        else               { PIN(); WAIT_VM(0); PIN(); }
        proc_tile(sB, k + 1, lane, myDot, myS1, myS2);
    }

    // deferred tail: lane k (k<16) owns row gwave + k*NWAVES
    int myT = 0;
    if (lane < STEPS) myT = target[gwave + lane * NWAVES];

    float d = myDot / fmaxf(sqrtf(myS1) * sqrtf(myS2), EPS);
    float posv = 0.0f, negv = 0.0f;
    int pc = 0;
    if (lane < STEPS) {
        if (myT == 1) { posv = 4.0f * softplusf(-0.5f * (d - 0.5f)); pc = 1; }
        else          { negv = 0.04f * softplusf(50.0f * (d - 2.0f)); }
    }

    #pragma unroll
    for (int off = 32; off > 0; off >>= 1) {
        posv += __shfl_xor(posv, off);
        negv += __shfl_xor(negv, off);
        pc   += __shfl_xor(pc, off);
    }

    if (lane == 0) { sPos[wave] = posv; sNeg[wave] = negv; sCnt[wave] = pc; }
    __syncthreads();
    if (threadIdx.x == 0) {
        float p = sPos[0] + sPos[1] + sPos[2] + sPos[3];
        float n = sNeg[0] + sNeg[1] + sNeg[2] + sNeg[3];
        int c = sCnt[0] + sCnt[1] + sCnt[2] + sCnt[3];
        atomicAdd(&sums[0], p);
        atomicAdd(&sums[1], n);
        atomicAdd(&icnt[0], c);
        __threadfence();
        unsigned int old = atomicAdd(done, 1u);
        if (old == (unsigned int)(gridDim.x - 1)) {
            __threadfence();
            float ps = __hip_atomic_load(&sums[0], __ATOMIC_RELAXED, __HIP_MEMORY_SCOPE_AGENT);
            float ns = __hip_atomic_load(&sums[1], __ATOMIC_RELAXED, __HIP_MEMORY_SCOPE_AGENT);
            int np = __hip_atomic_load(&icnt[0], __ATOMIC_RELAXED, __HIP_MEMORY_SCOPE_AGENT);
            int nn = N_ROWS - np;
            out[0] = ps / (float)(np > 1 ? np : 1) + ns / (float)(nn > 1 ? nn : 1);
        }
    }
}

extern "C" void kernel_launch(void* const* d_in, const int* in_sizes, int n_in,
                              void* d_out, int out_size, void* d_ws, size_t ws_size,
                              hipStream_t stream) {
    const float* o1 = (const float*)d_in[0];
    const float* o2 = (const float*)d_in[1];
    const int* tgt = (const int*)d_in[2];
    float* out = (float*)d_out;
    float* sums = (float*)d_ws;
    int* cnt = (int*)((char*)d_ws + 8);
    unsigned int* done = (unsigned int*)((char*)d_ws + 12);

    hipMemsetAsync(d_ws, 0, 16, stream);
    binloss_main<<<BLOCKS, 256, 0, stream>>>(o1, o2, tgt, sums, cnt, done, out);
}